// Round 1
// baseline (119.655 us; speedup 1.0000x reference)
//
#include <hip/hip_runtime.h>
#include <math.h>

// Problem constants
#define BB   8
#define NDET 200
#define NDP  208      // dets padded to 13*16
#define NCH  13       // det chunks of 16
#define KK   32
#define HP   138
#define WP   138
#define NXT  9        // x tiles of 16 (covers 144 >= 138)
#define NYP  69       // row pairs
#define NP   (HP*WP)
#define H0   550
#define W0   550
#define NPIX (H0*W0)
#define CC   3
#define POSEPS 1e-6f

typedef __attribute__((ext_vector_type(8))) short  short8;
typedef __attribute__((ext_vector_type(4))) float  floatx4;

// Workspace layout (bytes):
//  afrag: BB*NCH*64*16                 = 106,496 @ 0          bf16 A-frags of mask
//  gxf:   BB*NXT*NCH*64*16 (FRAG order)= 958,464 @ 106,496    exp(-dx^2*ia), lane-major
//  gyc:   BB*HP*NDP*4  (det-inner)     = 918,528 @ 1,064,960  conf*exp(-dy^2*ib)
//  fconf: NP*BB*4      (batch-inner)   = 609,408 @ 1,983,488
#define OFF_AFRAG 0
#define OFF_GX    106496
#define OFF_GYC   1064960
#define OFF_FCONF 1983488

extern "C" __device__ float __builtin_amdgcn_rcpf(float);  // v_rcp_f32

__device__ inline unsigned short f32_to_bf16(float f) {
    union { float f; unsigned u; } v; v.f = f;
    unsigned r = v.u + 0x7FFFu + ((v.u >> 16) & 1u);   // RNE
    return (unsigned short)(r >> 16);
}

// ---------------------------------------------------------------------------
// prep: gaussian tables + bf16 mask A-fragments + out=0.
// gx is now stored in WAVE-FRAGMENT order [b][xt][c][lane][r] so conf's
// per-chunk gx load is one contiguous coalesced 1 KiB transaction
// (previously: 64 lanes hitting 64 chunks strided 832 B -> diverged load).
// ---------------------------------------------------------------------------
__global__ __launch_bounds__(256) void prep_kernel(
    const float* __restrict__ loc,   // [B,NDET,4]
    const float* __restrict__ conf,  // [B,NDET]
    const float* __restrict__ mask,  // [B,NDET,KK]
    char* __restrict__ ws,
    float* __restrict__ out)
{
    const int idx = blockIdx.x * 256 + threadIdx.x;
    if (idx == 0) out[0] = 0.0f;     // replaces a memset dispatch
    const int W1 = BB * NXT * NCH * 64 * 4;  // 239,616 gx floats (frag order)
    const int W2 = BB * HP * NDP;            // 229,632 gyc floats
    if (idx < W1) {
        // flat = (((b*NXT+xt)*NCH + c)*64 + L)*4 + r
        const int r  = idx & 3;
        const int L  = (idx >> 2) & 63;
        const int t  = idx >> 8;             // (b*NXT+xt)*NCH + c
        const int c  = t % NCH;
        const int bx = t / NCH;
        const int xt = bx % NXT;
        const int b  = bx / NXT;
        const int n  = c * 16 + (L >> 4) * 4 + r;      // det
        const int x  = min(xt * 16 + (L & 15), WP - 1); // bake conf's xl clamp
        float v = 0.0f;
        if (n < NDET) {
            const float* l = loc + (b * NDET + n) * 4;
            float cx = l[0];
            float w  = fmaxf(l[2], 1e-3f);
            float ia = 1.0f / (2.0f * w * w);
            float dx = (x + 0.5f) * (1.0f / WP) - cx;
            v = __expf(-dx * dx * ia);
        }
        ((float*)(ws + OFF_GX))[idx] = v;
    } else if (idx < W1 + W2) {
        int k = idx - W1;
        int b = k / (HP * NDP); int r = k - b * (HP * NDP);
        int y = r / NDP;        int n = r - y * NDP;
        float v = 0.0f;
        if (n < NDET) {
            const float* l = loc + (b * NDET + n) * 4;
            float cy = l[1];
            float h  = fmaxf(l[3], 1e-3f);
            float ib = 1.0f / (2.0f * h * h);
            float dy = (y + 0.5f) * (1.0f / HP) - cy;
            v = conf[b * NDET + n] * __expf(-dy * dy * ib);
        }
        ((float*)(ws + OFF_GYC))[k] = v;
    } else if (idx < W1 + W2 + BB * NCH * 64) {
        int k = idx - W1 - W2;         // (b*NCH + c)*64 + L
        int L = k & 63; int bc = k >> 6;
        int c = bc % NCH; int b = bc / NCH;
        int det = c * 16 + (L & 15);
        int k0  = (L >> 4) * 8;
        unsigned o[4] = {0u, 0u, 0u, 0u};
        if (det < NDET) {
            const float* m = mask + (b * NDET + det) * KK + k0;
#pragma unroll
            for (int j = 0; j < 4; j++) {
                unsigned lo = f32_to_bf16(m[2 * j]);
                unsigned hi = f32_to_bf16(m[2 * j + 1]);
                o[j] = lo | (hi << 16);
            }
        }
        unsigned* dst = (unsigned*)(ws + OFF_AFRAG) + k * 4;
        dst[0] = o[0]; dst[1] = o[1]; dst[2] = o[2]; dst[3] = o[3];
    }
}

// ---------------------------------------------------------------------------
// conf (hot): one wave = a ROW-PAIR (y0r,y1r) x 16 pixels x 208 dets.
// Two mfma_f32_16x16x32_bf16 per det-chunk sharing the A-fragment.
// D mapping: pixel = lane&15, det-in-chunk = (lane>>4)*4 + reg.
// All three per-chunk table loads are now coalesced or broadcast:
//   af  : lane-contiguous 1 KiB          (unchanged)
//   gxf : lane-contiguous 1 KiB          (NEW frag layout)
//   gy  : quad-broadcast 64 B per row    (unchanged)
// ---------------------------------------------------------------------------
__global__ __launch_bounds__(256) void conf_kernel(
    const float* __restrict__ proto,  // [B,HP,WP,KK]
    const char* __restrict__ ws,
    float* __restrict__ fconf)        // [NP][BB]
{
    const int w   = blockIdx.x * 4 + (threadIdx.x >> 6);
    const int L   = threadIdx.x & 63;
    const int b   = w / (NYP * NXT);
    int rem       = w - b * (NYP * NXT);
    const int yp  = rem / NXT;
    const int xt  = rem - yp * NXT;
    const int y0r = yp * 2, y1r = y0r + 1;
    const int x0  = xt * 16;
    const int q   = L >> 4;
    const int c15 = L & 15;
    const int xl  = min(x0 + c15, WP - 1);   // clamp (discarded on store)

    const short8*  af  = (const short8*)(ws + OFF_AFRAG) + (size_t)b * NCH * 64 + L;
    const floatx4* gxf = (const floatx4*)(ws + OFF_GX)
                         + ((size_t)(b * NXT + xt) * NCH) * 64 + L;
    const floatx4* gy0 = (const floatx4*)(ws + OFF_GYC) + ((size_t)b * HP + y0r) * (NDP / 4);
    const floatx4* gy1 = (const floatx4*)(ws + OFF_GYC) + ((size_t)b * HP + y1r) * (NDP / 4);

    // B fragments: proto[b][y][xl][q*8 .. q*8+7] for both rows
    const float* pp0 = proto + (((size_t)b * HP + y0r) * WP + xl) * KK + q * 8;
    const float* pp1 = pp0 + (size_t)WP * KK;
    short8 bf0, bf1;
#pragma unroll
    for (int j = 0; j < 8; j++) {
        bf0[j] = (short)f32_to_bf16(pp0[j]);
        bf1[j] = (short)f32_to_bf16(pp1[j]);
    }

    float s10 = 0.f, s20 = 0.f, s11 = 0.f, s21 = 0.f;
#pragma unroll 2
    for (int c = 0; c < NCH; c++) {
        short8 a = af[c * 64];
        floatx4 d0 = {0.f, 0.f, 0.f, 0.f};
        floatx4 d1 = {0.f, 0.f, 0.f, 0.f};
        d0 = __builtin_amdgcn_mfma_f32_16x16x32_bf16(a, bf0, d0, 0, 0, 0);
        d1 = __builtin_amdgcn_mfma_f32_16x16x32_bf16(a, bf1, d1, 0, 0, 0);
        const floatx4 gxv  = gxf[c * 64];
        const floatx4 gy0v = gy0[c * 4 + q];
        const floatx4 gy1v = gy1[c * 4 + q];
#pragma unroll
        for (int r = 0; r < 4; r++) {
            // sigmoid(d) = 1/(1+exp(-d))  (single v_rcp_f32, 1ulp-ish: fine
            // under the 2%-relative scalar threshold)
            const float sig0 = __builtin_amdgcn_rcpf(1.0f + __expf(-d0[r]));
            const float mc0  = sig0 * (gxv[r] * gy0v[r]);
            s10 += mc0;
            s20 = fmaf(mc0, mc0, s20);
            const float sig1 = __builtin_amdgcn_rcpf(1.0f + __expf(-d1[r]));
            const float mc1  = sig1 * (gxv[r] * gy1v[r]);
            s11 += mc1;
            s21 = fmaf(mc1, mc1, s21);
        }
    }
    // reduce across the 4 quads (same pixel = same lane&15)
    s10 += __shfl_xor(s10, 16, 64); s10 += __shfl_xor(s10, 32, 64);
    s20 += __shfl_xor(s20, 16, 64); s20 += __shfl_xor(s20, 32, 64);
    s11 += __shfl_xor(s11, 16, 64); s11 += __shfl_xor(s11, 32, 64);
    s21 += __shfl_xor(s21, 16, 64); s21 += __shfl_xor(s21, 32, 64);
    if (q == 0 && x0 + c15 < WP) {
        float f0 = 1.0f - s20 / (s10 + POSEPS);
        float f1 = 1.0f - s21 / (s11 + POSEPS);
        if (isnan(f0)) f0 = 0.0f;
        if (isnan(f1)) f1 = 0.0f;
        fconf[((size_t)y0r * WP + x0 + c15) * BB + b] = f0;
        fconf[((size_t)y1r * WP + x0 + c15) * BB + b] = f1;
    }
}

// ---------------------------------------------------------------------------
// var: one block per output HALF-ROW (1100 blocks, was 550 -> 2.15 waves/SIMD
// was the occupancy floor; now 4.3). y-interp params are block-uniform; the
// two fconf source rows are staged in LDS (8.8 KB). Single-pass variance:
//   sum_b r*(o-m)^2 = sum(r*o^2) - (sum(r*o))^2 / t
// ---------------------------------------------------------------------------
__global__ __launch_bounds__(256) void var_kernel(
    const float* __restrict__ original, // [B,C,H0,W0]
    const float* __restrict__ fconf,    // [NP][BB]
    float* __restrict__ out)
{
    const int i    = blockIdx.x >> 1;   // output row
    const int half = blockIdx.x & 1;    // which 275-px half of the row
    const float sc  = (float)HP / (float)H0;
    const float syf = (i + 0.5f) * sc - 0.5f;
    const float fy0 = floorf(syf);
    const float wy  = syf - fy0;
    const int y0 = max((int)fy0, 0);
    const int y1 = min((int)fy0 + 1, HP - 1);

    __shared__ float lds[2 * WP * BB];  // 2 rows x 138 px x 8 batches
    {
        const floatx4* s0 = (const floatx4*)(fconf + (size_t)y0 * WP * BB);
        const floatx4* s1 = (const floatx4*)(fconf + (size_t)y1 * WP * BB);
        floatx4* l4 = (floatx4*)lds;
        for (int t = threadIdx.x; t < WP * 2; t += 256) {
            l4[t] = s0[t];
            l4[WP * 2 + t] = s1[t];
        }
    }
    __syncthreads();
    const floatx4* l4 = (const floatx4*)lds;

    const int jbeg = half * (W0 / 2);
    const int jend = jbeg + (W0 / 2);
    float v = 0.0f;
    for (int j = jbeg + threadIdx.x; j < jend; j += 256) {
        const float sxf = (j + 0.5f) * sc - 0.5f;
        const float fx0 = floorf(sxf);
        const float wx  = sxf - fx0;
        const int x0 = max((int)fx0, 0);
        const int x1 = min((int)fx0 + 1, WP - 1);

        const floatx4 a00 = l4[x0 * 2],          b00 = l4[x0 * 2 + 1];
        const floatx4 a01 = l4[x1 * 2],          b01 = l4[x1 * 2 + 1];
        const floatx4 a10 = l4[WP * 2 + x0 * 2], b10 = l4[WP * 2 + x0 * 2 + 1];
        const floatx4 a11 = l4[WP * 2 + x1 * 2], b11 = l4[WP * 2 + x1 * 2 + 1];
        const float w00 = (1.0f - wy) * (1.0f - wx);
        const float w01 = (1.0f - wy) * wx;
        const float w10 = wy * (1.0f - wx);
        const float w11 = wy * wx;

        float r[BB];
        float t = 0.0f;
#pragma unroll
        for (int e = 0; e < 4; e++) {
            float rb = w00 * a00[e] + w01 * a01[e] + w10 * a10[e] + w11 * a11[e];
            r[e] = rb; t += rb;
        }
#pragma unroll
        for (int e = 0; e < 4; e++) {
            float rb = w00 * b00[e] + w01 * b01[e] + w10 * b10[e] + w11 * b11[e];
            r[4 + e] = rb; t += rb;
        }
        const float inv_t  = __fdividef(1.0f, t);           // mean divisor (no eps)
        const float inv_te = __fdividef(1.0f, t + POSEPS);  // var divisor (+eps)
        float acc = 0.0f;
#pragma unroll
        for (int c = 0; c < CC; c++) {
            float sro = 0.0f, sroo = 0.0f;
#pragma unroll
            for (int bb = 0; bb < BB; bb++) {
                const float o  = original[(size_t)(bb * CC + c) * NPIX + (size_t)i * W0 + j];
                const float ro = r[bb] * o;
                sro += ro;
                sroo = fmaf(ro, o, sroo);
            }
            acc += sroo - sro * sro * inv_t;
        }
        v += acc * inv_te;
    }
    // block reduction
    for (int off = 32; off > 0; off >>= 1) v += __shfl_down(v, off, 64);
    __shared__ float red[4];
    const int lane = threadIdx.x & 63;
    const int wid  = threadIdx.x >> 6;
    if (lane == 0) red[wid] = v;
    __syncthreads();
    if (threadIdx.x == 0) {
        const float s = red[0] + red[1] + red[2] + red[3];
        atomicAdd(out, s * 0.25f);  // / K * B = * 8/32
    }
}

// ---------------------------------------------------------------------------
extern "C" void kernel_launch(void* const* d_in, const int* in_sizes, int n_in,
                              void* d_out, int out_size, void* d_ws, size_t ws_size,
                              hipStream_t stream) {
    const float* original = (const float*)d_in[0]; // [8,3,550,550]
    const float* loc      = (const float*)d_in[1]; // [8,200,4]
    const float* mask     = (const float*)d_in[2]; // [8,200,32]
    const float* conf     = (const float*)d_in[3]; // [8,200]
    const float* proto    = (const float*)d_in[4]; // [8,138,138,32]
    float* out = (float*)d_out;
    char* ws = (char*)d_ws;
    float* fconf = (float*)(ws + OFF_FCONF);

    // gx frag-order floats + gyc floats + afrag threads
    const int prep_total = BB * NXT * NCH * 64 * 4 + BB * HP * NDP + BB * NCH * 64; // 475,904
    prep_kernel<<<(prep_total + 255) / 256, 256, 0, stream>>>(loc, conf, mask, ws, out);

    // 8 b * 69 row-pairs * 9 xtiles = 4968 waves, 4 waves/block
    conf_kernel<<<(BB * NYP * NXT) / 4, 256, 0, stream>>>(proto, ws, fconf);

    // 550 rows x 2 half-rows
    var_kernel<<<H0 * 2, 256, 0, stream>>>(original, fconf, out);
}

// Round 2
// 114.913 us; speedup vs baseline: 1.0413x; 1.0413x over previous
//
#include <hip/hip_runtime.h>
#include <math.h>

// Problem constants
#define BB   8
#define NDET 200
#define NDP  208      // dets padded to 13*16
#define NCH  13       // det chunks of 16
#define KK   32
#define HP   138
#define WP   138
#define NXT  9        // x tiles of 16 (covers 144 >= 138)
#define NYP  69       // row pairs
#define NP   (HP*WP)
#define H0   550
#define W0   550
#define NPIX (H0*W0)
#define CC   3
#define POSEPS 1e-6f

typedef __attribute__((ext_vector_type(8))) short  short8;
typedef __attribute__((ext_vector_type(4))) float  floatx4;
typedef __attribute__((ext_vector_type(2))) float  floatx2;

// Workspace layout (bytes):
//  afrag: BB*NCH*64*16                 = 106,496 @ 0          bf16 A-frags of mask
//  gxf:   BB*NXT*NCH*64*16 (FRAG order)= 958,464 @ 106,496    exp(-dx^2*ia), lane-major
//  gyc:   BB*HP*NDP*4  (det-inner)     = 918,528 @ 1,064,960  conf*exp(-dy^2*ib)
//  fconf: NP*BB*4      (batch-inner)   = 609,408 @ 1,983,488
#define OFF_AFRAG 0
#define OFF_GX    106496
#define OFF_GYC   1064960
#define OFF_FCONF 1983488

extern "C" __device__ float __builtin_amdgcn_rcpf(float);  // v_rcp_f32

__device__ inline unsigned short f32_to_bf16(float f) {
    union { float f; unsigned u; } v; v.f = f;
    unsigned r = v.u + 0x7FFFu + ((v.u >> 16) & 1u);   // RNE
    return (unsigned short)(r >> 16);
}

// ---------------------------------------------------------------------------
// prep: gaussian tables + bf16 mask A-fragments + out=0.
// gx is stored in WAVE-FRAGMENT order [b][xt][c][lane][r] so conf's
// per-chunk gx load is one contiguous coalesced 1 KiB transaction.
// ---------------------------------------------------------------------------
__global__ __launch_bounds__(256) void prep_kernel(
    const float* __restrict__ loc,   // [B,NDET,4]
    const float* __restrict__ conf,  // [B,NDET]
    const float* __restrict__ mask,  // [B,NDET,KK]
    char* __restrict__ ws,
    float* __restrict__ out)
{
    const int idx = blockIdx.x * 256 + threadIdx.x;
    if (idx == 0) out[0] = 0.0f;     // replaces a memset dispatch
    const int W1 = BB * NXT * NCH * 64 * 4;  // 239,616 gx floats (frag order)
    const int W2 = BB * HP * NDP;            // 229,632 gyc floats
    if (idx < W1) {
        // flat = (((b*NXT+xt)*NCH + c)*64 + L)*4 + r
        const int r  = idx & 3;
        const int L  = (idx >> 2) & 63;
        const int t  = idx >> 8;             // (b*NXT+xt)*NCH + c
        const int c  = t % NCH;
        const int bx = t / NCH;
        const int xt = bx % NXT;
        const int b  = bx / NXT;
        const int n  = c * 16 + (L >> 4) * 4 + r;      // det
        const int x  = min(xt * 16 + (L & 15), WP - 1); // bake conf's xl clamp
        float v = 0.0f;
        if (n < NDET) {
            const float* l = loc + (b * NDET + n) * 4;
            float cx = l[0];
            float w  = fmaxf(l[2], 1e-3f);
            float ia = 1.0f / (2.0f * w * w);
            float dx = (x + 0.5f) * (1.0f / WP) - cx;
            v = __expf(-dx * dx * ia);
        }
        ((float*)(ws + OFF_GX))[idx] = v;
    } else if (idx < W1 + W2) {
        int k = idx - W1;
        int b = k / (HP * NDP); int r = k - b * (HP * NDP);
        int y = r / NDP;        int n = r - y * NDP;
        float v = 0.0f;
        if (n < NDET) {
            const float* l = loc + (b * NDET + n) * 4;
            float cy = l[1];
            float h  = fmaxf(l[3], 1e-3f);
            float ib = 1.0f / (2.0f * h * h);
            float dy = (y + 0.5f) * (1.0f / HP) - cy;
            v = conf[b * NDET + n] * __expf(-dy * dy * ib);
        }
        ((float*)(ws + OFF_GYC))[k] = v;
    } else if (idx < W1 + W2 + BB * NCH * 64) {
        int k = idx - W1 - W2;         // (b*NCH + c)*64 + L
        int L = k & 63; int bc = k >> 6;
        int c = bc % NCH; int b = bc / NCH;
        int det = c * 16 + (L & 15);
        int k0  = (L >> 4) * 8;
        unsigned o[4] = {0u, 0u, 0u, 0u};
        if (det < NDET) {
            const float* m = mask + (b * NDET + det) * KK + k0;
#pragma unroll
            for (int j = 0; j < 4; j++) {
                unsigned lo = f32_to_bf16(m[2 * j]);
                unsigned hi = f32_to_bf16(m[2 * j + 1]);
                o[j] = lo | (hi << 16);
            }
        }
        unsigned* dst = (unsigned*)(ws + OFF_AFRAG) + k * 4;
        dst[0] = o[0]; dst[1] = o[1]; dst[2] = o[2]; dst[3] = o[3];
    }
}

// ---------------------------------------------------------------------------
// conf (hot): one wave = a ROW-PAIR (y0r,y1r) x 16 pixels x 208 dets.
// Two mfma_f32_16x16x32_bf16 per det-chunk sharing the A-fragment.
// D mapping: pixel = lane&15, det-in-chunk = (lane>>4)*4 + reg.
// All three per-chunk table loads are coalesced or broadcast:
//   af  : lane-contiguous 1 KiB
//   gxf : lane-contiguous 1 KiB (frag layout)
//   gy  : quad-broadcast 64 B per row
// ---------------------------------------------------------------------------
__global__ __launch_bounds__(256) void conf_kernel(
    const float* __restrict__ proto,  // [B,HP,WP,KK]
    const char* __restrict__ ws,
    float* __restrict__ fconf)        // [NP][BB]
{
    const int w   = blockIdx.x * 4 + (threadIdx.x >> 6);
    const int L   = threadIdx.x & 63;
    const int b   = w / (NYP * NXT);
    int rem       = w - b * (NYP * NXT);
    const int yp  = rem / NXT;
    const int xt  = rem - yp * NXT;
    const int y0r = yp * 2, y1r = y0r + 1;
    const int x0  = xt * 16;
    const int q   = L >> 4;
    const int c15 = L & 15;
    const int xl  = min(x0 + c15, WP - 1);   // clamp (discarded on store)

    const short8*  af  = (const short8*)(ws + OFF_AFRAG) + (size_t)b * NCH * 64 + L;
    const floatx4* gxf = (const floatx4*)(ws + OFF_GX)
                         + ((size_t)(b * NXT + xt) * NCH) * 64 + L;
    const floatx4* gy0 = (const floatx4*)(ws + OFF_GYC) + ((size_t)b * HP + y0r) * (NDP / 4);
    const floatx4* gy1 = (const floatx4*)(ws + OFF_GYC) + ((size_t)b * HP + y1r) * (NDP / 4);

    // B fragments: proto[b][y][xl][q*8 .. q*8+7] for both rows
    const float* pp0 = proto + (((size_t)b * HP + y0r) * WP + xl) * KK + q * 8;
    const float* pp1 = pp0 + (size_t)WP * KK;
    short8 bf0, bf1;
#pragma unroll
    for (int j = 0; j < 8; j++) {
        bf0[j] = (short)f32_to_bf16(pp0[j]);
        bf1[j] = (short)f32_to_bf16(pp1[j]);
    }

    float s10 = 0.f, s20 = 0.f, s11 = 0.f, s21 = 0.f;
#pragma unroll 2
    for (int c = 0; c < NCH; c++) {
        short8 a = af[c * 64];
        floatx4 d0 = {0.f, 0.f, 0.f, 0.f};
        floatx4 d1 = {0.f, 0.f, 0.f, 0.f};
        d0 = __builtin_amdgcn_mfma_f32_16x16x32_bf16(a, bf0, d0, 0, 0, 0);
        d1 = __builtin_amdgcn_mfma_f32_16x16x32_bf16(a, bf1, d1, 0, 0, 0);
        const floatx4 gxv  = gxf[c * 64];
        const floatx4 gy0v = gy0[c * 4 + q];
        const floatx4 gy1v = gy1[c * 4 + q];
#pragma unroll
        for (int r = 0; r < 4; r++) {
            // sigmoid(d) = 1/(1+exp(-d))  (single v_rcp_f32, 1ulp-ish: fine
            // under the 2%-relative scalar threshold)
            const float sig0 = __builtin_amdgcn_rcpf(1.0f + __expf(-d0[r]));
            const float mc0  = sig0 * (gxv[r] * gy0v[r]);
            s10 += mc0;
            s20 = fmaf(mc0, mc0, s20);
            const float sig1 = __builtin_amdgcn_rcpf(1.0f + __expf(-d1[r]));
            const float mc1  = sig1 * (gxv[r] * gy1v[r]);
            s11 += mc1;
            s21 = fmaf(mc1, mc1, s21);
        }
    }
    // reduce across the 4 quads (same pixel = same lane&15)
    s10 += __shfl_xor(s10, 16, 64); s10 += __shfl_xor(s10, 32, 64);
    s20 += __shfl_xor(s20, 16, 64); s20 += __shfl_xor(s20, 32, 64);
    s11 += __shfl_xor(s11, 16, 64); s11 += __shfl_xor(s11, 32, 64);
    s21 += __shfl_xor(s21, 16, 64); s21 += __shfl_xor(s21, 32, 64);
    if (q == 0 && x0 + c15 < WP) {
        float f0 = 1.0f - s20 / (s10 + POSEPS);
        float f1 = 1.0f - s21 / (s11 + POSEPS);
        if (isnan(f0)) f0 = 0.0f;
        if (isnan(f1)) f1 = 0.0f;
        fconf[((size_t)y0r * WP + x0 + c15) * BB + b] = f0;
        fconf[((size_t)y1r * WP + x0 + c15) * BB + b] = f1;
    }
}

// ---------------------------------------------------------------------------
// var: one block per output row (550 blocks — the half-row split regressed,
// reverted). Pixels processed in PAIRS per thread: original[] is read with
// dwordx2 (row stride 2200 B and plane stride 1.21 MB are 8B-multiples, so
// every pair load is aligned) — halves load-issue count and caps the
// longest per-thread chain at 2 pair-iterations (was 3 scalar).
// Single-pass variance: sum_b r*(o-m)^2 = sum(r*o^2) - (sum(r*o))^2 / t
// ---------------------------------------------------------------------------
__global__ __launch_bounds__(256) void var_kernel(
    const float* __restrict__ original, // [B,C,H0,W0]
    const float* __restrict__ fconf,    // [NP][BB]
    float* __restrict__ out)
{
    const int i = blockIdx.x;           // output row
    const float sc  = (float)HP / (float)H0;
    const float syf = (i + 0.5f) * sc - 0.5f;
    const float fy0 = floorf(syf);
    const float wy  = syf - fy0;
    const int y0 = max((int)fy0, 0);
    const int y1 = min((int)fy0 + 1, HP - 1);

    __shared__ float lds[2 * WP * BB];  // 2 rows x 138 px x 8 batches
    {
        const floatx4* s0 = (const floatx4*)(fconf + (size_t)y0 * WP * BB);
        const floatx4* s1 = (const floatx4*)(fconf + (size_t)y1 * WP * BB);
        floatx4* l4 = (floatx4*)lds;
        for (int t = threadIdx.x; t < WP * 2; t += 256) {
            l4[t] = s0[t];
            l4[WP * 2 + t] = s1[t];
        }
    }
    __syncthreads();
    const floatx4* l4 = (const floatx4*)lds;

    float v = 0.0f;
    for (int p = threadIdx.x; p < W0 / 2; p += 256) {
        const int j0 = 2 * p;
        // ---- bilinear weights for both pixels of the pair ----
        float rA[BB], rBp[BB];   // resized conf for j0, j0+1
        float tA, tB;
        {
            const float w1y = wy, w0y = 1.0f - wy;
#pragma unroll
            for (int s = 0; s < 2; s++) {
                const int j = j0 + s;
                const float sxf = (j + 0.5f) * sc - 0.5f;
                const float fx0 = floorf(sxf);
                const float wx  = sxf - fx0;
                const int x0 = max((int)fx0, 0);
                const int x1 = min((int)fx0 + 1, WP - 1);
                const floatx4 a00 = l4[x0 * 2],          b00 = l4[x0 * 2 + 1];
                const floatx4 a01 = l4[x1 * 2],          b01 = l4[x1 * 2 + 1];
                const floatx4 a10 = l4[WP * 2 + x0 * 2], b10 = l4[WP * 2 + x0 * 2 + 1];
                const floatx4 a11 = l4[WP * 2 + x1 * 2], b11 = l4[WP * 2 + x1 * 2 + 1];
                const float w00 = w0y * (1.0f - wx);
                const float w01 = w0y * wx;
                const float w10 = w1y * (1.0f - wx);
                const float w11 = w1y * wx;
                float* r = s ? rBp : rA;
                float t = 0.0f;
#pragma unroll
                for (int e = 0; e < 4; e++) {
                    float rb = w00 * a00[e] + w01 * a01[e] + w10 * a10[e] + w11 * a11[e];
                    r[e] = rb; t += rb;
                }
#pragma unroll
                for (int e = 0; e < 4; e++) {
                    float rb = w00 * b00[e] + w01 * b01[e] + w10 * b10[e] + w11 * b11[e];
                    r[4 + e] = rb; t += rb;
                }
                if (s) tB = t; else tA = t;
            }
        }
        const float invA  = __fdividef(1.0f, tA);
        const float invAe = __fdividef(1.0f, tA + POSEPS);
        const float invB  = __fdividef(1.0f, tB);
        const float invBe = __fdividef(1.0f, tB + POSEPS);

        float accA = 0.0f, accB = 0.0f;
#pragma unroll
        for (int c = 0; c < CC; c++) {
            float sroA = 0.0f, srooA = 0.0f;
            float sroB = 0.0f, srooB = 0.0f;
#pragma unroll
            for (int bb = 0; bb < BB; bb++) {
                const floatx2 o2 = *(const floatx2*)(
                    original + (size_t)(bb * CC + c) * NPIX + (size_t)i * W0 + j0);
                const float roA = rA[bb]  * o2[0];
                const float roB = rBp[bb] * o2[1];
                sroA += roA;  srooA = fmaf(roA, o2[0], srooA);
                sroB += roB;  srooB = fmaf(roB, o2[1], srooB);
            }
            accA += srooA - sroA * sroA * invA;
            accB += srooB - sroB * sroB * invB;
        }
        v += accA * invAe + accB * invBe;
    }
    // block reduction
    for (int off = 32; off > 0; off >>= 1) v += __shfl_down(v, off, 64);
    __shared__ float red[4];
    const int lane = threadIdx.x & 63;
    const int wid  = threadIdx.x >> 6;
    if (lane == 0) red[wid] = v;
    __syncthreads();
    if (threadIdx.x == 0) {
        const float s = red[0] + red[1] + red[2] + red[3];
        atomicAdd(out, s * 0.25f);  // / K * B = * 8/32
    }
}

// ---------------------------------------------------------------------------
extern "C" void kernel_launch(void* const* d_in, const int* in_sizes, int n_in,
                              void* d_out, int out_size, void* d_ws, size_t ws_size,
                              hipStream_t stream) {
    const float* original = (const float*)d_in[0]; // [8,3,550,550]
    const float* loc      = (const float*)d_in[1]; // [8,200,4]
    const float* mask     = (const float*)d_in[2]; // [8,200,32]
    const float* conf     = (const float*)d_in[3]; // [8,200]
    const float* proto    = (const float*)d_in[4]; // [8,138,138,32]
    float* out = (float*)d_out;
    char* ws = (char*)d_ws;
    float* fconf = (float*)(ws + OFF_FCONF);

    // gx frag-order floats + gyc floats + afrag threads
    const int prep_total = BB * NXT * NCH * 64 * 4 + BB * HP * NDP + BB * NCH * 64; // 475,904
    prep_kernel<<<(prep_total + 255) / 256, 256, 0, stream>>>(loc, conf, mask, ws, out);

    // 8 b * 69 row-pairs * 9 xtiles = 4968 waves, 4 waves/block
    conf_kernel<<<(BB * NYP * NXT) / 4, 256, 0, stream>>>(proto, ws, fconf);

    var_kernel<<<H0, 256, 0, stream>>>(original, fconf, out);
}